// Round 1
// 709.031 us; speedup vs baseline: 1.0280x; 1.0280x over previous
//
#include <hip/hip_runtime.h>
#include <math.h>

typedef __bf16 bf16_t;
typedef __bf16 bf16x8 __attribute__((ext_vector_type(8)));
typedef __bf16 bf16x4v __attribute__((ext_vector_type(4)));
typedef float f32x4 __attribute__((ext_vector_type(4)));

#define MFMA16x16(a, b, c) __builtin_amdgcn_mfma_f32_16x16x32_bf16((a), (b), (c), 0, 0, 0)

#define MASK_VAL -1000.0f
#define LOG2E 1.4426950408889634f
#define SH2 28.853900817779268f   /* 20 * log2(e): shift in exp2 domain */

// ---------------- prep kernels ----------------

// qin[m][e] = bf16(query[m][e] + pe(s, e)), m = s*4+b. One thread = 8 consecutive e of one row
// -> bf16x8 (16B) store instead of 8 scalar 2B stores.
__global__ __launch_bounds__(256) void prep_qpe(const float* __restrict__ query,
                                                bf16_t* __restrict__ qin) {
    int idx = blockIdx.x * 256 + threadIdx.x;   // 524288 threads
    int m = idx >> 6;                            // row 0..8191 (= s*4+b)
    int e0 = (idx & 63) << 3;                    // 8-elem chunk
    int s = m >> 2;
    const float C = 9.210340371976184f / 512.0f;  // ln(10000)/512
    const float* qp = query + (size_t)m * 512 + e0;
    float4 v0 = *(const float4*)qp;
    float4 v1 = *(const float4*)(qp + 4);
    float pe[8];
    #pragma unroll
    for (int p = 0; p < 4; p++) {
        float freq = __expf(-(float)(e0 + 2 * p) * C);
        sincosf((float)s * freq, &pe[2 * p], &pe[2 * p + 1]);
    }
    bf16x8 o;
    o[0] = (bf16_t)(v0.x + pe[0]); o[1] = (bf16_t)(v0.y + pe[1]);
    o[2] = (bf16_t)(v0.z + pe[2]); o[3] = (bf16_t)(v0.w + pe[3]);
    o[4] = (bf16_t)(v1.x + pe[4]); o[5] = (bf16_t)(v1.y + pe[5]);
    o[6] = (bf16_t)(v1.z + pe[6]); o[7] = (bf16_t)(v1.w + pe[7]);
    *(bf16x8*)(qin + (size_t)m * 512 + e0) = o;
}

__global__ __launch_bounds__(256) void prep_kcast(const float* __restrict__ key,
                                                  bf16_t* __restrict__ kin) {
    int idx = blockIdx.x * 256 + threadIdx.x;   // 1048576 threads, 4 elems each
    float4 v = ((const float4*)key)[idx];
    bf16x4v o;
    o.x = (bf16_t)v.x; o.y = (bf16_t)v.y; o.z = (bf16_t)v.z; o.w = (bf16_t)v.w;
    ((bf16x4v*)kin)[idx] = o;
}

// Transposed bf16 weight slices: wqt[j][e] = Wq[e][j] (j in [0,256)),
//                                wkt[j][e] = Wk[e][256+j]
__global__ __launch_bounds__(256) void prep_wt(const float* __restrict__ Wq,
                                               const float* __restrict__ Wk,
                                               bf16_t* __restrict__ wqt,
                                               bf16_t* __restrict__ wkt) {
    int idx = blockIdx.x * 256 + threadIdx.x;   // 262144 threads
    int t = idx & 131071;
    int j = t >> 9, e = t & 511;
    if (idx < 131072) wqt[t] = (bf16_t)Wq[e * 544 + j];
    else              wkt[t] = (bf16_t)Wk[e * 544 + 256 + j];
}

// OR-reduce masks into a flag (so the all-False case takes a branch-free fast path)
__global__ __launch_bounds__(256) void mask_any(const uint4* __restrict__ am,
                                                const uint4* __restrict__ kpm,
                                                int* __restrict__ flag) {
    int idx = blockIdx.x * 256 + threadIdx.x;
    unsigned int v = 0;
    if (idx < 262144) { uint4 x = am[idx]; v = x.x | x.y | x.z | x.w; }
    else if (idx < 262656) { uint4 x = kpm[idx - 262144]; v = x.x | x.y | x.z | x.w; }
    if (v) atomicOr(flag, 1);
}

// ---------------- projection GEMM ----------------
// C[m][n] = sum_k A[m][k]*Bt[n][k] + bias[n];  M=8192, N=256, K=512
// Output layout: Out[((h*4+b)*2048 + s)*32 + d], m = s*4+b, n = h*32+d  (MFMA-frag-friendly)
__global__ __launch_bounds__(256) void proj_gemm(const bf16_t* __restrict__ A,
                                                 const bf16_t* __restrict__ Bt,
                                                 const float* __restrict__ bias,
                                                 bf16_t* __restrict__ Out) {
    int lane = threadIdx.x & 63;
    int wave = threadIdx.x >> 6;
    int wm = wave & 1, wn = wave >> 1;
    int m0 = blockIdx.x * 64 + wm * 32;
    int n0 = blockIdx.y * 64 + wn * 32;
    int lrow = lane & 15, quad = lane >> 4;
    f32x4 acc00 = {0.f, 0.f, 0.f, 0.f};
    f32x4 acc01 = acc00, acc10 = acc00, acc11 = acc00;
    const bf16_t* Ab = A + (size_t)(m0 + lrow) * 512 + quad * 8;
    const bf16_t* Bb = Bt + (size_t)(n0 + lrow) * 512 + quad * 8;
    #pragma unroll 4
    for (int k0 = 0; k0 < 512; k0 += 32) {
        bf16x8 a0 = *(const bf16x8*)(Ab + k0);
        bf16x8 a1 = *(const bf16x8*)(Ab + 16 * 512 + k0);
        bf16x8 b0 = *(const bf16x8*)(Bb + k0);
        bf16x8 b1 = *(const bf16x8*)(Bb + 16 * 512 + k0);
        acc00 = MFMA16x16(a0, b0, acc00);
        acc01 = MFMA16x16(a0, b1, acc01);
        acc10 = MFMA16x16(a1, b0, acc10);
        acc11 = MFMA16x16(a1, b1, acc11);
    }
    #pragma unroll
    for (int i = 0; i < 2; i++) {
        #pragma unroll
        for (int j = 0; j < 2; j++) {
            f32x4 acc = (i == 0) ? (j == 0 ? acc00 : acc01) : (j == 0 ? acc10 : acc11);
            int col = n0 + j * 16 + lrow;
            float bv = bias[col];
            int h = col >> 5, d = col & 31;
            #pragma unroll
            for (int r = 0; r < 4; r++) {
                int row = m0 + i * 16 + quad * 4 + r;
                int s = row >> 2, bb = row & 3;
                Out[(size_t)((h * 4 + bb) * 2048 + s) * 32 + d] = (bf16_t)(acc[r] + bv);
            }
        }
    }
}

// ---------------- fused scores + softmax ----------------
// grid: (32 q-tiles, 32 hb). Block = 4 waves; each wave owns 16 q rows.
// Operand-SWAPPED MFMA: acc = mfma(Kfrag, Qfrag) gives acc[r] = S[q0+lrow][t0+quad*4+r]
//  -> each lane owns ONE output row, 4 consecutive cols per tile:
//     f32x4 nontemporal stores, scalar m/l, 2-step cross-quad reduction.
// Pass 1: running max + sum of exp2(s*log2e - SH2). Pass 2: recompute, write
//     exp2(fma(s, log2e, -C2)) with C2 = M2 + log2(l)  (normalization folded into exponent).
template <bool MASKED>
__device__ __forceinline__ void attn_core(const bf16_t* __restrict__ Qb,
                                          const bf16_t* __restrict__ Kb,
                                          const unsigned char* __restrict__ am,
                                          const unsigned char* __restrict__ kpm,
                                          float* __restrict__ out) {
    int lane = threadIdx.x & 63;
    int wave = threadIdx.x >> 6;
    int hb = blockIdx.y;
    int b = hb & 3;
    int q0 = blockIdx.x * 64 + wave * 16;
    int lrow = lane & 15, quad = lane >> 4;
    int row = q0 + lrow;                 // this lane's output row
    // B-operand: Q rows q0..q0+15; lane holds Q[q0+lrow][quad*8..+7]  (loaded once)
    bf16x8 qfrag = *(const bf16x8*)(Qb + (size_t)(hb * 2048 + row) * 32 + quad * 8);
    // A-operand stream: K rows t0+lrow
    const bf16_t* kptr = Kb + (size_t)hb * 2048 * 32 + (size_t)lrow * 32 + quad * 8;
    const unsigned char* amrow = MASKED ? am + (size_t)row * 2048 + quad * 4 : nullptr;
    const unsigned char* kpmb  = MASKED ? kpm + (size_t)b * 2048 + quad * 4 : nullptr;

    float m = -1e30f, l = 0.f;
    #pragma unroll 4
    for (int t0 = 0; t0 < 2048; t0 += 16) {
        bf16x8 kfrag = *(const bf16x8*)(kptr + (size_t)t0 * 32);
        f32x4 acc = {0.f, 0.f, 0.f, 0.f};
        acc = MFMA16x16(kfrag, qfrag, acc);   // acc[r] = S[row][t0+quad*4+r]
        if (MASKED) {
            uchar4 a4 = *(const uchar4*)(amrow + t0);
            uchar4 k4 = *(const uchar4*)(kpmb + t0);
            if (a4.x | k4.x) acc[0] = MASK_VAL;
            if (a4.y | k4.y) acc[1] = MASK_VAL;
            if (a4.z | k4.z) acc[2] = MASK_VAL;
            if (a4.w | k4.w) acc[3] = MASK_VAL;
        }
        m = fmaxf(m, fmaxf(fmaxf(acc[0], acc[1]), fmaxf(acc[2], acc[3])));
        l += exp2f(fmaf(acc[0], LOG2E, -SH2)) + exp2f(fmaf(acc[1], LOG2E, -SH2))
           + exp2f(fmaf(acc[2], LOG2E, -SH2)) + exp2f(fmaf(acc[3], LOG2E, -SH2));
    }
    // reduce across the 4 quads owning this row (lanes lrow, +16, +32, +48)
    m = fmaxf(m, __shfl_xor(m, 16)); l += __shfl_xor(l, 16);
    m = fmaxf(m, __shfl_xor(m, 32)); l += __shfl_xor(l, 32);

    float M2, lf;
    if (__any((l == 0.0f) || (m > 80.0f))) {
        // rare stable path (fully-masked rows or huge scores): recompute sum vs true max
        float mL = m * LOG2E;
        float l2 = 0.f;
        for (int t0 = 0; t0 < 2048; t0 += 16) {
            bf16x8 kfrag = *(const bf16x8*)(kptr + (size_t)t0 * 32);
            f32x4 acc = {0.f, 0.f, 0.f, 0.f};
            acc = MFMA16x16(kfrag, qfrag, acc);
            if (MASKED) {
                uchar4 a4 = *(const uchar4*)(amrow + t0);
                uchar4 k4 = *(const uchar4*)(kpmb + t0);
                if (a4.x | k4.x) acc[0] = MASK_VAL;
                if (a4.y | k4.y) acc[1] = MASK_VAL;
                if (a4.z | k4.z) acc[2] = MASK_VAL;
                if (a4.w | k4.w) acc[3] = MASK_VAL;
            }
            l2 += exp2f(fmaf(acc[0], LOG2E, -mL)) + exp2f(fmaf(acc[1], LOG2E, -mL))
                + exp2f(fmaf(acc[2], LOG2E, -mL)) + exp2f(fmaf(acc[3], LOG2E, -mL));
        }
        l2 += __shfl_xor(l2, 16);
        l2 += __shfl_xor(l2, 32);
        M2 = mL; lf = l2;    // l2 >= 1 (row contains its own max)
    } else {
        M2 = SH2; lf = l;
    }
    float C2 = M2 + log2f(lf);   // exp2(s*log2e - C2) = exp(s - M)/l

    // pass 2: recompute scores, write normalized probs as f32x4 per lane
    float* orow = out + (size_t)hb * 2048 * 2048 + (size_t)row * 2048 + quad * 4;
    #pragma unroll 4
    for (int t0 = 0; t0 < 2048; t0 += 16) {
        bf16x8 kfrag = *(const bf16x8*)(kptr + (size_t)t0 * 32);
        f32x4 acc = {0.f, 0.f, 0.f, 0.f};
        acc = MFMA16x16(kfrag, qfrag, acc);
        if (MASKED) {
            uchar4 a4 = *(const uchar4*)(amrow + t0);
            uchar4 k4 = *(const uchar4*)(kpmb + t0);
            if (a4.x | k4.x) acc[0] = MASK_VAL;
            if (a4.y | k4.y) acc[1] = MASK_VAL;
            if (a4.z | k4.z) acc[2] = MASK_VAL;
            if (a4.w | k4.w) acc[3] = MASK_VAL;
        }
        f32x4 o;
        o[0] = exp2f(fmaf(acc[0], LOG2E, -C2));
        o[1] = exp2f(fmaf(acc[1], LOG2E, -C2));
        o[2] = exp2f(fmaf(acc[2], LOG2E, -C2));
        o[3] = exp2f(fmaf(acc[3], LOG2E, -C2));
        __builtin_nontemporal_store(o, (f32x4*)(orow + t0));
    }
}

// Split kernels so the hot (unmasked) path compiles with its own (small) register
// budget and guaranteed 4 blocks/CU; each guards on the device-side mask flag.
__global__ __launch_bounds__(256, 4) void attn_nomask(const bf16_t* __restrict__ Qb,
                                                      const bf16_t* __restrict__ Kb,
                                                      const int* __restrict__ flag,
                                                      float* __restrict__ out) {
    if (*flag) return;
    attn_core<false>(Qb, Kb, nullptr, nullptr, out);
}

__global__ __launch_bounds__(256) void attn_masked(const bf16_t* __restrict__ Qb,
                                                   const bf16_t* __restrict__ Kb,
                                                   const unsigned char* __restrict__ am,
                                                   const unsigned char* __restrict__ kpm,
                                                   const int* __restrict__ flag,
                                                   float* __restrict__ out) {
    if (!*flag) return;
    attn_core<true>(Qb, Kb, am, kpm, out);
}

// ---------------- launcher ----------------
extern "C" void kernel_launch(void* const* d_in, const int* in_sizes, int n_in,
                              void* d_out, int out_size, void* d_ws, size_t ws_size,
                              hipStream_t stream) {
    const float* query = (const float*)d_in[0];
    const float* key   = (const float*)d_in[1];
    const float* Wq    = (const float*)d_in[2];
    const float* bq    = (const float*)d_in[3];
    const float* Wk    = (const float*)d_in[4];
    const float* bk    = (const float*)d_in[5];
    const unsigned char* kpm = (const unsigned char*)d_in[6];
    const unsigned char* am  = (const unsigned char*)d_in[7];
    float* out = (float*)d_out;

    char* ws = (char*)d_ws;
    bf16_t* qin = (bf16_t*)(ws);                              //  8 MiB  [8192][512]
    bf16_t* kin = (bf16_t*)(ws + (8u << 20));                 //  8 MiB
    bf16_t* wqt = (bf16_t*)(ws + (16u << 20));                //  256 KiB [256][512]
    bf16_t* wkt = (bf16_t*)(ws + (16u << 20) + (256u << 10)); //  256 KiB
    bf16_t* Qb  = (bf16_t*)(ws + (17u << 20));                //  4 MiB  [hb][2048][32]
    bf16_t* Kb  = (bf16_t*)(ws + (21u << 20));                //  4 MiB
    int* flag   = (int*)(ws + (25u << 20));

    hipMemsetAsync(flag, 0, 4, stream);
    prep_qpe<<<2048, 256, 0, stream>>>(query, qin);
    prep_kcast<<<4096, 256, 0, stream>>>(key, kin);
    prep_wt<<<1024, 256, 0, stream>>>(Wq, Wk, wqt, wkt);
    mask_any<<<1026, 256, 0, stream>>>((const uint4*)am, (const uint4*)kpm, flag);
    proj_gemm<<<dim3(128, 4), 256, 0, stream>>>(qin, wqt, bq, Qb);
    proj_gemm<<<dim3(128, 4), 256, 0, stream>>>(kin, wkt, bk + 256, Kb);
    attn_nomask<<<dim3(32, 32), 256, 0, stream>>>(Qb, Kb, flag, out);
    attn_masked<<<dim3(32, 32), 256, 0, stream>>>(Qb, Kb, am, kpm, flag, out);
}

// Round 3
// 666.243 us; speedup vs baseline: 1.0941x; 1.0642x over previous
//
#include <hip/hip_runtime.h>
#include <math.h>

typedef __bf16 bf16_t;
typedef __bf16 bf16x8 __attribute__((ext_vector_type(8)));
typedef __bf16 bf16x4v __attribute__((ext_vector_type(4)));
typedef float f32x4 __attribute__((ext_vector_type(4)));

#define MFMA16x16(a, b, c) __builtin_amdgcn_mfma_f32_16x16x32_bf16((a), (b), (c), 0, 0, 0)

#define MASK_VAL -1000.0f
#define LOG2E 1.4426950408889634f
#define SH2 28.853900817779268f   /* 20 * log2(e): shift in exp2 domain */

// ---------------- prep kernels ----------------

// qin[m][e] = bf16(query[m][e] + pe(s, e)), m = s*4+b. One thread = 8 consecutive e of one row
__global__ __launch_bounds__(256) void prep_qpe(const float* __restrict__ query,
                                                bf16_t* __restrict__ qin) {
    int idx = blockIdx.x * 256 + threadIdx.x;   // 524288 threads
    int m = idx >> 6;                            // row 0..8191 (= s*4+b)
    int e0 = (idx & 63) << 3;                    // 8-elem chunk
    int s = m >> 2;
    const float C = 9.210340371976184f / 512.0f;  // ln(10000)/512
    const float* qp = query + (size_t)m * 512 + e0;
    float4 v0 = *(const float4*)qp;
    float4 v1 = *(const float4*)(qp + 4);
    float pe[8];
    #pragma unroll
    for (int p = 0; p < 4; p++) {
        float freq = __expf(-(float)(e0 + 2 * p) * C);
        sincosf((float)s * freq, &pe[2 * p], &pe[2 * p + 1]);
    }
    bf16x8 o;
    o[0] = (bf16_t)(v0.x + pe[0]); o[1] = (bf16_t)(v0.y + pe[1]);
    o[2] = (bf16_t)(v0.z + pe[2]); o[3] = (bf16_t)(v0.w + pe[3]);
    o[4] = (bf16_t)(v1.x + pe[4]); o[5] = (bf16_t)(v1.y + pe[5]);
    o[6] = (bf16_t)(v1.z + pe[6]); o[7] = (bf16_t)(v1.w + pe[7]);
    *(bf16x8*)(qin + (size_t)m * 512 + e0) = o;
}

__global__ __launch_bounds__(256) void prep_kcast(const float* __restrict__ key,
                                                  bf16_t* __restrict__ kin) {
    int idx = blockIdx.x * 256 + threadIdx.x;   // 1048576 threads, 4 elems each
    float4 v = ((const float4*)key)[idx];
    bf16x4v o;
    o.x = (bf16_t)v.x; o.y = (bf16_t)v.y; o.z = (bf16_t)v.z; o.w = (bf16_t)v.w;
    ((bf16x4v*)kin)[idx] = o;
}

// Transposed bf16 weight slices: wqt[j][e] = Wq[e][j] (j in [0,256)),
//                                wkt[j][e] = Wk[e][256+j]
__global__ __launch_bounds__(256) void prep_wt(const float* __restrict__ Wq,
                                               const float* __restrict__ Wk,
                                               bf16_t* __restrict__ wqt,
                                               bf16_t* __restrict__ wkt) {
    int idx = blockIdx.x * 256 + threadIdx.x;   // 262144 threads
    int t = idx & 131071;
    int j = t >> 9, e = t & 511;
    if (idx < 131072) wqt[t] = (bf16_t)Wq[e * 544 + j];
    else              wkt[t] = (bf16_t)Wk[e * 544 + 256 + j];
}

// OR-reduce masks into a flag (so the all-False case takes a branch-free fast path)
__global__ __launch_bounds__(256) void mask_any(const uint4* __restrict__ am,
                                                const uint4* __restrict__ kpm,
                                                int* __restrict__ flag) {
    int idx = blockIdx.x * 256 + threadIdx.x;
    unsigned int v = 0;
    if (idx < 262144) { uint4 x = am[idx]; v = x.x | x.y | x.z | x.w; }
    else if (idx < 262656) { uint4 x = kpm[idx - 262144]; v = x.x | x.y | x.z | x.w; }
    if (v) atomicOr(flag, 1);
}

// ---------------- projection GEMM ----------------
// C[m][n] = sum_k A[m][k]*Bt[n][k] + bias[n];  M=8192, N=256, K=512
// Output layout: Out[((h*4+b)*2048 + s)*32 + d], m = s*4+b, n = h*32+d  (MFMA-frag-friendly)
__global__ __launch_bounds__(256) void proj_gemm(const bf16_t* __restrict__ A,
                                                 const bf16_t* __restrict__ Bt,
                                                 const float* __restrict__ bias,
                                                 bf16_t* __restrict__ Out) {
    int lane = threadIdx.x & 63;
    int wave = threadIdx.x >> 6;
    int wm = wave & 1, wn = wave >> 1;
    int m0 = blockIdx.x * 64 + wm * 32;
    int n0 = blockIdx.y * 64 + wn * 32;
    int lrow = lane & 15, quad = lane >> 4;
    f32x4 acc00 = {0.f, 0.f, 0.f, 0.f};
    f32x4 acc01 = acc00, acc10 = acc00, acc11 = acc00;
    const bf16_t* Ab = A + (size_t)(m0 + lrow) * 512 + quad * 8;
    const bf16_t* Bb = Bt + (size_t)(n0 + lrow) * 512 + quad * 8;
    #pragma unroll 4
    for (int k0 = 0; k0 < 512; k0 += 32) {
        bf16x8 a0 = *(const bf16x8*)(Ab + k0);
        bf16x8 a1 = *(const bf16x8*)(Ab + 16 * 512 + k0);
        bf16x8 b0 = *(const bf16x8*)(Bb + k0);
        bf16x8 b1 = *(const bf16x8*)(Bb + 16 * 512 + k0);
        acc00 = MFMA16x16(a0, b0, acc00);
        acc01 = MFMA16x16(a0, b1, acc01);
        acc10 = MFMA16x16(a1, b0, acc10);
        acc11 = MFMA16x16(a1, b1, acc11);
    }
    #pragma unroll
    for (int i = 0; i < 2; i++) {
        #pragma unroll
        for (int j = 0; j < 2; j++) {
            f32x4 acc = (i == 0) ? (j == 0 ? acc00 : acc01) : (j == 0 ? acc10 : acc11);
            int col = n0 + j * 16 + lrow;
            float bv = bias[col];
            int h = col >> 5, d = col & 31;
            #pragma unroll
            for (int r = 0; r < 4; r++) {
                int row = m0 + i * 16 + quad * 4 + r;
                int s = row >> 2, bb = row & 3;
                Out[(size_t)((h * 4 + bb) * 2048 + s) * 32 + d] = (bf16_t)(acc[r] + bv);
            }
        }
    }
}

// ---------------- fused scores + softmax ----------------
// grid: (32 q-tiles, 32 hb). Block = 4 waves; each wave owns 16 q rows.
// Operand-SWAPPED MFMA: acc = mfma(Kfrag, Qfrag) gives acc[r] = S[q0+lrow][t0+quad*4+r]
//  -> each lane owns ONE output row, 4 consecutive cols per tile.
// Pass 1: sum of exp2(s*log2e - SH2) only (no max tracking; validity = l>0 && finite).
// Pass 2: recompute, write exp2(fma(s, log2e, -C2)) with C2 = M2 + log2(l).
// Stores are PLAIN (cached) so L2 merges the per-iteration 64B row-segments into
// full-line HBM writebacks (nontemporal was causing partial-line write amplification).
template <bool MASKED>
__device__ __forceinline__ void attn_core(const bf16_t* __restrict__ Qb,
                                          const bf16_t* __restrict__ Kb,
                                          const unsigned char* __restrict__ am,
                                          const unsigned char* __restrict__ kpm,
                                          float* __restrict__ out) {
    int lane = threadIdx.x & 63;
    int wave = threadIdx.x >> 6;
    int hb = blockIdx.y;
    int b = hb & 3;
    int q0 = blockIdx.x * 64 + wave * 16;
    int lrow = lane & 15, quad = lane >> 4;
    int row = q0 + lrow;                 // this lane's output row
    // B-operand: Q rows q0..q0+15; lane holds Q[q0+lrow][quad*8..+7]  (loaded once)
    bf16x8 qfrag = *(const bf16x8*)(Qb + (size_t)(hb * 2048 + row) * 32 + quad * 8);
    // A-operand stream: K rows t0+lrow
    const bf16_t* kptr = Kb + (size_t)hb * 2048 * 32 + (size_t)lrow * 32 + quad * 8;
    const unsigned char* amrow = MASKED ? am + (size_t)row * 2048 + quad * 4 : nullptr;
    const unsigned char* kpmb  = MASKED ? kpm + (size_t)b * 2048 + quad * 4 : nullptr;

    float l = 0.f;
    #pragma unroll 4
    for (int t0 = 0; t0 < 2048; t0 += 16) {
        bf16x8 kfrag = *(const bf16x8*)(kptr + (size_t)t0 * 32);
        f32x4 acc = {0.f, 0.f, 0.f, 0.f};
        acc = MFMA16x16(kfrag, qfrag, acc);   // acc[r] = S[row][t0+quad*4+r]
        if (MASKED) {
            uchar4 a4 = *(const uchar4*)(amrow + t0);
            uchar4 k4 = *(const uchar4*)(kpmb + t0);
            if (a4.x | k4.x) acc[0] = MASK_VAL;
            if (a4.y | k4.y) acc[1] = MASK_VAL;
            if (a4.z | k4.z) acc[2] = MASK_VAL;
            if (a4.w | k4.w) acc[3] = MASK_VAL;
        }
        l += exp2f(fmaf(acc[0], LOG2E, -SH2)) + exp2f(fmaf(acc[1], LOG2E, -SH2))
           + exp2f(fmaf(acc[2], LOG2E, -SH2)) + exp2f(fmaf(acc[3], LOG2E, -SH2));
    }
    // reduce across the 4 quads owning this row (lanes lrow, +16, +32, +48)
    l += __shfl_xor(l, 16);
    l += __shfl_xor(l, 32);

    float M2, lf;
    if (__any(!(l > 0.0f && l < 3.0e38f))) {
        // rare stable path (fully-masked rows, all-tiny or huge scores):
        // recompute true row max, then the sum against it. Cold.
        float mx = -1e30f;
        for (int t0 = 0; t0 < 2048; t0 += 16) {
            bf16x8 kfrag = *(const bf16x8*)(kptr + (size_t)t0 * 32);
            f32x4 acc = {0.f, 0.f, 0.f, 0.f};
            acc = MFMA16x16(kfrag, qfrag, acc);
            if (MASKED) {
                uchar4 a4 = *(const uchar4*)(amrow + t0);
                uchar4 k4 = *(const uchar4*)(kpmb + t0);
                if (a4.x | k4.x) acc[0] = MASK_VAL;
                if (a4.y | k4.y) acc[1] = MASK_VAL;
                if (a4.z | k4.z) acc[2] = MASK_VAL;
                if (a4.w | k4.w) acc[3] = MASK_VAL;
            }
            mx = fmaxf(mx, fmaxf(fmaxf(acc[0], acc[1]), fmaxf(acc[2], acc[3])));
        }
        mx = fmaxf(mx, __shfl_xor(mx, 16));
        mx = fmaxf(mx, __shfl_xor(mx, 32));
        float mL = mx * LOG2E;
        float l2 = 0.f;
        for (int t0 = 0; t0 < 2048; t0 += 16) {
            bf16x8 kfrag = *(const bf16x8*)(kptr + (size_t)t0 * 32);
            f32x4 acc = {0.f, 0.f, 0.f, 0.f};
            acc = MFMA16x16(kfrag, qfrag, acc);
            if (MASKED) {
                uchar4 a4 = *(const uchar4*)(amrow + t0);
                uchar4 k4 = *(const uchar4*)(kpmb + t0);
                if (a4.x | k4.x) acc[0] = MASK_VAL;
                if (a4.y | k4.y) acc[1] = MASK_VAL;
                if (a4.z | k4.z) acc[2] = MASK_VAL;
                if (a4.w | k4.w) acc[3] = MASK_VAL;
            }
            l2 += exp2f(fmaf(acc[0], LOG2E, -mL)) + exp2f(fmaf(acc[1], LOG2E, -mL))
                + exp2f(fmaf(acc[2], LOG2E, -mL)) + exp2f(fmaf(acc[3], LOG2E, -mL));
        }
        l2 += __shfl_xor(l2, 16);
        l2 += __shfl_xor(l2, 32);
        M2 = mL; lf = l2;    // l2 >= 1 (row contains its own max)
    } else {
        M2 = SH2; lf = l;
    }
    float C2 = M2 + log2f(lf);   // exp2(s*log2e - C2) = exp(s - M)/l

    // pass 2: recompute scores, write normalized probs as f32x4 per lane (cached stores)
    float* orow = out + (size_t)hb * 2048 * 2048 + (size_t)row * 2048 + quad * 4;
    #pragma unroll 4
    for (int t0 = 0; t0 < 2048; t0 += 16) {
        bf16x8 kfrag = *(const bf16x8*)(kptr + (size_t)t0 * 32);
        f32x4 acc = {0.f, 0.f, 0.f, 0.f};
        acc = MFMA16x16(kfrag, qfrag, acc);
        if (MASKED) {
            uchar4 a4 = *(const uchar4*)(amrow + t0);
            uchar4 k4 = *(const uchar4*)(kpmb + t0);
            if (a4.x | k4.x) acc[0] = MASK_VAL;
            if (a4.y | k4.y) acc[1] = MASK_VAL;
            if (a4.z | k4.z) acc[2] = MASK_VAL;
            if (a4.w | k4.w) acc[3] = MASK_VAL;
        }
        f32x4 o;
        o[0] = exp2f(fmaf(acc[0], LOG2E, -C2));
        o[1] = exp2f(fmaf(acc[1], LOG2E, -C2));
        o[2] = exp2f(fmaf(acc[2], LOG2E, -C2));
        o[3] = exp2f(fmaf(acc[3], LOG2E, -C2));
        *(f32x4*)(orow + t0) = o;
    }
}

// Split kernels so the hot (unmasked) path compiles with its own (small) register
// budget and guaranteed 4 blocks/CU; each guards on the device-side mask flag.
__global__ __launch_bounds__(256, 4) void attn_nomask(const bf16_t* __restrict__ Qb,
                                                      const bf16_t* __restrict__ Kb,
                                                      const int* __restrict__ flag,
                                                      float* __restrict__ out) {
    if (*flag) return;
    attn_core<false>(Qb, Kb, nullptr, nullptr, out);
}

__global__ __launch_bounds__(256) void attn_masked(const bf16_t* __restrict__ Qb,
                                                   const bf16_t* __restrict__ Kb,
                                                   const unsigned char* __restrict__ am,
                                                   const unsigned char* __restrict__ kpm,
                                                   const int* __restrict__ flag,
                                                   float* __restrict__ out) {
    if (!*flag) return;
    attn_core<true>(Qb, Kb, am, kpm, out);
}

// ---------------- launcher ----------------
extern "C" void kernel_launch(void* const* d_in, const int* in_sizes, int n_in,
                              void* d_out, int out_size, void* d_ws, size_t ws_size,
                              hipStream_t stream) {
    const float* query = (const float*)d_in[0];
    const float* key   = (const float*)d_in[1];
    const float* Wq    = (const float*)d_in[2];
    const float* bq    = (const float*)d_in[3];
    const float* Wk    = (const float*)d_in[4];
    const float* bk    = (const float*)d_in[5];
    const unsigned char* kpm = (const unsigned char*)d_in[6];
    const unsigned char* am  = (const unsigned char*)d_in[7];
    float* out = (float*)d_out;

    char* ws = (char*)d_ws;
    bf16_t* qin = (bf16_t*)(ws);                              //  8 MiB  [8192][512]
    bf16_t* kin = (bf16_t*)(ws + (8u << 20));                 //  8 MiB
    bf16_t* wqt = (bf16_t*)(ws + (16u << 20));                //  256 KiB [256][512]
    bf16_t* wkt = (bf16_t*)(ws + (16u << 20) + (256u << 10)); //  256 KiB
    bf16_t* Qb  = (bf16_t*)(ws + (17u << 20));                //  4 MiB  [hb][2048][32]
    bf16_t* Kb  = (bf16_t*)(ws + (21u << 20));                //  4 MiB
    int* flag   = (int*)(ws + (25u << 20));

    hipMemsetAsync(flag, 0, 4, stream);
    prep_qpe<<<2048, 256, 0, stream>>>(query, qin);
    prep_kcast<<<4096, 256, 0, stream>>>(key, kin);
    prep_wt<<<1024, 256, 0, stream>>>(Wq, Wk, wqt, wkt);
    mask_any<<<1026, 256, 0, stream>>>((const uint4*)am, (const uint4*)kpm, flag);
    proj_gemm<<<dim3(128, 4), 256, 0, stream>>>(qin, wqt, bq, Qb);
    proj_gemm<<<dim3(128, 4), 256, 0, stream>>>(kin, wkt, bk + 256, Kb);
    attn_nomask<<<dim3(32, 32), 256, 0, stream>>>(Qb, Kb, flag, out);
    attn_masked<<<dim3(32, 32), 256, 0, stream>>>(Qb, Kb, am, kpm, flag, out);
}